// Round 7
// baseline (734.610 us; speedup 1.0000x reference)
//
#include <hip/hip_runtime.h>

#define NB 4
#define CH 512
#define NPIX 4096
#define GSZ 16
#define KVB 32
#define NT (NPIX / KVB)          // 128 kv tiles
#define DYN_LDS 68096            // 32K K + 32K V + 2K P + 512B exch (single-buf)

typedef __attribute__((ext_vector_type(8))) short bf16x8;
typedef __attribute__((ext_vector_type(4))) short bf16x4;
typedef __attribute__((ext_vector_type(4))) float f32x4;

#define MFMA __builtin_amdgcn_mfma_f32_16x16x32_bf16

static __device__ __forceinline__ short f2bf(float f) {
  unsigned u = __builtin_bit_cast(unsigned, f);
  u += 0x7fffu + ((u >> 16) & 1u);
  return (short)(u >> 16);
}

static __device__ __forceinline__ float bperm_f(int srclane, float v) {
  int r = __builtin_amdgcn_ds_bpermute(srclane << 2, __builtin_bit_cast(int, v));
  return __builtin_bit_cast(float, r);
}

typedef __attribute__((address_space(1))) unsigned glob_u32;
typedef __attribute__((address_space(3))) unsigned lds_u32;
static __device__ __forceinline__ void gl_lds16(const void* g, void* l) {
  __builtin_amdgcn_global_load_lds((const glob_u32*)g, (lds_u32*)l, 16, 0, 0);
}

// ---------------- kernel 1: weights fp32 -> bf16 (q,k,v stacked; proj separate)
__global__ __launch_bounds__(256) void wconv_kernel(
    const float* __restrict__ qw, const float* __restrict__ kw,
    const float* __restrict__ vw, const float* __restrict__ pw,
    short* __restrict__ wstack, short* __restrict__ wp) {
  int idx = (blockIdx.x * 256 + threadIdx.x) * 4;
  int mat = idx >> 18;
  int off = idx & 262143;
  const float* src = (mat == 0) ? qw : (mat == 1) ? kw : (mat == 2) ? vw : pw;
  short* dst = (mat < 3) ? (wstack + (size_t)mat * 262144) : wp;
  float4 v = *reinterpret_cast<const float4*>(src + off);
  bf16x4 o;
  o[0] = f2bf(v.x); o[1] = f2bf(v.y); o[2] = f2bf(v.z); o[3] = f2bf(v.w);
  *reinterpret_cast<bf16x4*>(dst + off) = o;
}

// ---------------- kernel 2: GroupNorm + bf16 + transpose -> hT [B][N][C]
__global__ __launch_bounds__(256) void gn_kernel(
    const float* __restrict__ x, const float* __restrict__ nw,
    const float* __restrict__ nb, short* __restrict__ hT) {
  int b = blockIdx.x >> 5, g = blockIdx.x & 31;
  int tid = threadIdx.x;
  const float* base = x + (size_t)(b * CH + g * GSZ) * NPIX;
  const float4* b4 = reinterpret_cast<const float4*>(base);
  float s = 0.f, s2 = 0.f;
  for (int i = tid; i < GSZ * NPIX / 4; i += 256) {
    float4 v = b4[i];
    s += v.x + v.y + v.z + v.w;
    s2 += v.x * v.x + v.y * v.y + v.z * v.z + v.w * v.w;
  }
  #pragma unroll
  for (int m = 1; m < 64; m <<= 1) { s += __shfl_xor(s, m); s2 += __shfl_xor(s2, m); }
  __shared__ float red[8];
  if ((tid & 63) == 0) { red[(tid >> 6) * 2] = s; red[(tid >> 6) * 2 + 1] = s2; }
  __syncthreads();
  s = red[0] + red[2] + red[4] + red[6];
  s2 = red[1] + red[3] + red[5] + red[7];
  float mean = s * (1.f / 65536.f);
  float var = s2 * (1.f / 65536.f) - mean * mean;
  float rstd = rsqrtf(var + 1e-5f);
  int c = tid >> 4, nq = tid & 15;
  float wch = nw[g * GSZ + c] * rstd;
  float bch = nb[g * GSZ + c] - mean * wch;
  __shared__ short lt[GSZ][264];
  short* outb = hT + (size_t)b * NPIX * CH + g * GSZ;
  const float* srcc = base + (size_t)c * NPIX + nq * 16;
  for (int chunk = 0; chunk < 16; ++chunk) {
    const float4* sp = reinterpret_cast<const float4*>(srcc + chunk * 256);
    float4 v0 = sp[0], v1 = sp[1], v2 = sp[2], v3 = sp[3];
    bf16x8 w0, w1;
    w0[0] = f2bf(v0.x * wch + bch); w0[1] = f2bf(v0.y * wch + bch);
    w0[2] = f2bf(v0.z * wch + bch); w0[3] = f2bf(v0.w * wch + bch);
    w0[4] = f2bf(v1.x * wch + bch); w0[5] = f2bf(v1.y * wch + bch);
    w0[6] = f2bf(v1.z * wch + bch); w0[7] = f2bf(v1.w * wch + bch);
    w1[0] = f2bf(v2.x * wch + bch); w1[1] = f2bf(v2.y * wch + bch);
    w1[2] = f2bf(v2.z * wch + bch); w1[3] = f2bf(v2.w * wch + bch);
    w1[4] = f2bf(v3.x * wch + bch); w1[5] = f2bf(v3.y * wch + bch);
    w1[6] = f2bf(v3.z * wch + bch); w1[7] = f2bf(v3.w * wch + bch);
    *reinterpret_cast<bf16x8*>(&lt[c][nq * 16]) = w0;
    *reinterpret_cast<bf16x8*>(&lt[c][nq * 16 + 8]) = w1;
    __syncthreads();
    bf16x8 o0, o1;
    #pragma unroll
    for (int cc = 0; cc < 8; ++cc) o0[cc] = lt[cc][tid];
    #pragma unroll
    for (int cc = 0; cc < 8; ++cc) o1[cc] = lt[cc + 8][tid];
    short* orow = outb + (size_t)(chunk * 256 + tid) * CH;
    *reinterpret_cast<bf16x8*>(orow) = o0;
    *reinterpret_cast<bf16x8*>(orow + 8) = o1;
    __syncthreads();
  }
}

// ---------------- kernel 3: QKV GEMM (stacked M=1536) from hT token-major
// q output is pre-scaled by 512^-0.5
__global__ __launch_bounds__(256) void qkv_kernel(
    const short* __restrict__ wstack, const short* __restrict__ hT,
    const float* __restrict__ qb, const float* __restrict__ kb,
    const float* __restrict__ vb,
    short* __restrict__ qT, short* __restrict__ kT, short* __restrict__ vC) {
  int b = blockIdx.z;
  int tid = threadIdx.x;
  int lane = tid & 63, wid = tid >> 6;
  int l15 = lane & 15, lg = lane >> 4;
  int ob = blockIdx.y * 64 + (wid >> 1) * 32;
  int nbase = blockIdx.x * 64 + (wid & 1) * 32;
  const short* aptr = wstack + (size_t)(ob + l15) * CH + lg * 8;
  const short* bptr = hT + ((size_t)b * NPIX + nbase + l15) * CH + lg * 8;
  f32x4 acc[2][2];
  #pragma unroll
  for (int mi = 0; mi < 2; ++mi)
    #pragma unroll
    for (int ni = 0; ni < 2; ++ni) acc[mi][ni] = (f32x4){0.f, 0.f, 0.f, 0.f};
  #pragma unroll 4
  for (int kk = 0; kk < CH; kk += 32) {
    bf16x8 a0 = *reinterpret_cast<const bf16x8*>(aptr + kk);
    bf16x8 a1 = *reinterpret_cast<const bf16x8*>(aptr + 16 * CH + kk);
    bf16x8 b0 = *reinterpret_cast<const bf16x8*>(bptr + kk);
    bf16x8 b1 = *reinterpret_cast<const bf16x8*>(bptr + 16 * CH + kk);
    acc[0][0] = MFMA(a0, b0, acc[0][0], 0, 0, 0);
    acc[0][1] = MFMA(a0, b1, acc[0][1], 0, 0, 0);
    acc[1][0] = MFMA(a1, b0, acc[1][0], 0, 0, 0);
    acc[1][1] = MFMA(a1, b1, acc[1][1], 0, 0, 0);
  }
  int oglob = blockIdx.y * 64;
  #pragma unroll
  for (int mi = 0; mi < 2; ++mi) {
    int oo = ob + mi * 16 + lg * 4;
    #pragma unroll
    for (int ni = 0; ni < 2; ++ni) {
      int nn = nbase + ni * 16 + l15;
      f32x4 a = acc[mi][ni];
      if (oglob < 1024) {
        const float* bias = (oglob < 512) ? qb : kb;
        short* dstm = (oglob < 512) ? qT : kT;
        float sc = (oglob < 512) ? 0.044194173824159216f : 1.0f;
        int ol = oo & 511;
        bf16x4 pk;
        #pragma unroll
        for (int r = 0; r < 4; ++r) pk[r] = f2bf((a[r] + bias[ol + r]) * sc);
        *reinterpret_cast<bf16x4*>(dstm + ((size_t)b * NPIX + nn) * CH + ol) = pk;
      } else {
        int ov = oo - 1024;
        short* dstv = vC + ((size_t)b * CH + ov) * NPIX + nn;
        #pragma unroll
        for (int r = 0; r < 4; ++r) dstv[(size_t)r * NPIX] = f2bf(a[r] + vb[ov + r]);
      }
    }
  }
}

// ---------------- kernel 4: flash attention, 4 waves / 32 q-rows / block,
// single-buffered K/V (68KB LDS -> 2 blocks/CU), kv-split pairs, swapped
// QK^T (per-lane softmax), PV delayed one iter.
// qT(pre-scaled),kT: [B][N][C] bf16; vC: [B][C][N] bf16; ao: [B][N][C] bf16
__global__ __launch_bounds__(256, 2) void flash_kernel(
    const short* __restrict__ qT, const short* __restrict__ kT,
    const short* __restrict__ vC, short* __restrict__ ao) {
  extern __shared__ char smem[];
  char* kbuf = smem;                         // [32][1024B] K (XOR-swz)
  char* vbuf = smem + 32768;                 // [512][64B]  V (XOR-swz)
  char* pbuf = smem + 65536;                 // [2 pairs][16q][64B] P~ (XOR-swz)
  float* exch = (float*)(smem + 67584);      // [4 waves][16q][2] (m, psum)

  // XCD-aware swizzle: each XCD gets 64 consecutive logical blocks (half a
  // batch's q-range), so its L2 sees one batch's K/V working set.
  int lin = blockIdx.y * 128 + blockIdx.x;   // 0..511
  int sw = (lin & 7) * 64 + (lin >> 3);      // bijective (512 % 8 == 0)
  int qtile = sw & 127, b = sw >> 7;

  int tid = threadIdx.x;
  int lane = tid & 63, w = tid >> 6;         // 4 waves
  int p = w >> 1, h = w & 1;                 // pair, kv/d-half
  int l15 = lane & 15, lg = lane >> 4;
  int qrow = qtile * 32 + p * 16;

  const short* qptr = qT + ((size_t)b * NPIX + qrow + l15) * CH + lg * 8;
  bf16x8 qf[16];
  #pragma unroll
  for (int ks = 0; ks < 16; ++ks) qf[ks] = *reinterpret_cast<const bf16x8*>(qptr + ks * 32);

  f32x4 oacc[16];
  #pragma unroll
  for (int i = 0; i < 16; ++i) oacc[i] = (f32x4){0.f, 0.f, 0.f, 0.f};
  float mrow = -INFINITY, lrow = 0.f;        // per-lane: q = l15
  bf16x8 pa_prev;
  bf16x8 vf_prev[16];
  #pragma unroll
  for (int i = 0; i < 8; ++i) pa_prev[i] = 0;
  #pragma unroll
  for (int j = 0; j < 16; ++j)
    #pragma unroll
    for (int i = 0; i < 8; ++i) vf_prev[j][i] = 0;

  const short* kTb = kT + (size_t)b * NPIX * CH;
  const short* vCb = vC + (size_t)b * CH * NPIX;
  const int swz = (l15 & 7) << 4;
  const int vswz = ((l15 >> 1) & 3) << 4;
  const int pswz = (l15 & 3) << 4;
  char* ppair = pbuf + p * 1024;
  float* exw = exch + (w * 16 + l15) * 2;          // own slot
  float* exr = exch + ((w ^ 1) * 16 + l15) * 2;    // partner slot

  auto stage = [&](int t) {
    int m0 = t * KVB;
    #pragma unroll
    for (int i = 0; i < 8; ++i) {            // K rows (src pre-swizzled)
      int r = w * 8 + i;
      const short* src = kTb + (size_t)(m0 + r) * CH + ((lane ^ (r & 7)) * 8);
      gl_lds16(src, kbuf + r * 1024);
    }
    #pragma unroll
    for (int i = 0; i < 8; ++i) {            // V chunks (src pre-swizzled)
      int j = w * 8 + i;
      int ch = j * 16 + (lane >> 2);
      const short* src = vCb + (size_t)ch * NPIX + m0 +
                         (((lane & 3) ^ ((lane >> 3) & 3)) * 8);
      gl_lds16(src, vbuf + j * 1024);
    }
  };

  stage(0);
  asm volatile("s_waitcnt vmcnt(0)" ::: "memory");
  __syncthreads();

  for (int t = 0; t < NT; ++t) {
    // ---- 1. swapped QK: S^T[16kv(h), 16q] = K_h * Q^T
    f32x4 st = (f32x4){0.f, 0.f, 0.f, 0.f};
    __builtin_amdgcn_s_setprio(1);
    #pragma unroll
    for (int cs = 0; cs < 16; ++cs) {
      bf16x8 kf = *reinterpret_cast<const bf16x8*>(
          kbuf + (h * 16 + l15) * 1024 + ((cs * 64 + lg * 16) ^ swz));
      st = MFMA(kf, qf[cs], st, 0, 0, 0);
    }
    __builtin_amdgcn_s_setprio(0);
    // ---- 2. own-half reduce
    float tmax = fmaxf(fmaxf(st[0], st[1]), fmaxf(st[2], st[3]));
    tmax = fmaxf(tmax, __shfl_xor(tmax, 16));
    tmax = fmaxf(tmax, __shfl_xor(tmax, 32));
    float pr[4];
    float psh;
    pr[0] = __expf(st[0] - tmax); pr[1] = __expf(st[1] - tmax);
    pr[2] = __expf(st[2] - tmax); pr[3] = __expf(st[3] - tmax);
    psh = (pr[0] + pr[1]) + (pr[2] + pr[3]);
    psh += __shfl_xor(psh, 16);
    psh += __shfl_xor(psh, 32);
    if (lane < 16) { exw[0] = tmax; exw[1] = psh; }
    // ---- bar1: LDS-only drain (exchange visible)
    asm volatile("s_waitcnt lgkmcnt(0)" ::: "memory");
    __builtin_amdgcn_s_barrier();
    __builtin_amdgcn_sched_barrier(0);
    // ---- 3. combine with partner half
    float mo = exr[0], po = exr[1];
    float mnew = fmaxf(mrow, fmaxf(tmax, mo));
    float alpha = __expf(mrow - mnew);
    float scl = __expf(tmax - mnew);
    lrow = lrow * alpha + psh * scl + po * __expf(mo - mnew);
    mrow = mnew;
    // ---- 4. P~ = P_h * scl -> LDS
    {
      bf16x4 pk;
      pk[0] = f2bf(pr[0] * scl); pk[1] = f2bf(pr[1] * scl);
      pk[2] = f2bf(pr[2] * scl); pk[3] = f2bf(pr[3] * scl);
      *reinterpret_cast<bf16x4*>(ppair + l15 * 64 + ((h * 32 + lg * 8) ^ pswz)) = pk;
    }
    // ---- 5. PV(t-1) in registers, then rescale by alpha
    __builtin_amdgcn_s_setprio(1);
    #pragma unroll
    for (int j = 0; j < 16; ++j)
      oacc[j] = MFMA(pa_prev, vf_prev[j], oacc[j], 0, 0, 0);
    __builtin_amdgcn_s_setprio(0);
    if (!__all(alpha == 1.0f)) {
      float a4[4];
      #pragma unroll
      for (int r = 0; r < 4; ++r) a4[r] = bperm_f(lg * 4 + r, alpha);
      #pragma unroll
      for (int j = 0; j < 16; ++j) {
        oacc[j][0] *= a4[0]; oacc[j][1] *= a4[1];
        oacc[j][2] *= a4[2]; oacc[j][3] *= a4[3];
      }
    }
    // ---- 5.5 register prefetch of V(t) fragments (last reads of vbuf)
    #pragma unroll
    for (int j = 0; j < 16; ++j)
      vf_prev[j] = *reinterpret_cast<const bf16x8*>(
          vbuf + ((h * 16 + j) * 16 + l15) * 64 + ((lg * 16) ^ vswz));
    // ---- bar2: all reads of kbuf/vbuf complete block-wide; P~ visible
    asm volatile("s_waitcnt lgkmcnt(0)" ::: "memory");
    __builtin_amdgcn_s_barrier();
    __builtin_amdgcn_sched_barrier(0);
    // ---- 6. refill the (single) buffer with tile t+1
    if (t + 1 < NT) stage(t + 1);
    // ---- 7. P~(t) fragment for next-iter PV (pbuf: not touched by staging)
    pa_prev = *reinterpret_cast<const bf16x8*>(ppair + l15 * 64 + ((lg * 16) ^ pswz));
    // ---- bar3: staged tile visible
    asm volatile("s_waitcnt vmcnt(0) lgkmcnt(0)" ::: "memory");
    __builtin_amdgcn_s_barrier();
    __builtin_amdgcn_sched_barrier(0);
  }
  // ---- final PV for last tile
  #pragma unroll
  for (int j = 0; j < 16; ++j)
    oacc[j] = MFMA(pa_prev, vf_prev[j], oacc[j], 0, 0, 0);

  float linv = 1.f / lrow;
  float r4[4];
  #pragma unroll
  for (int r = 0; r < 4; ++r) r4[r] = bperm_f(lg * 4 + r, linv);
  short* aob = ao + ((size_t)b * NPIX + qrow) * CH;
  #pragma unroll
  for (int j = 0; j < 16; ++j) {
    int cb2 = h * 16 + j;
    #pragma unroll
    for (int r = 0; r < 4; ++r) {
      aob[(size_t)(lg * 4 + r) * CH + cb2 * 16 + l15] = f2bf(oacc[j][r] * r4[r]);
    }
  }
}

// ---------------- kernel 5: proj GEMM + bias + residual (fp32 out)
__global__ __launch_bounds__(256) void proj_kernel(
    const short* __restrict__ wpm, const short* __restrict__ ao,
    const float* __restrict__ x, const float* __restrict__ pb,
    float* __restrict__ out) {
  int b = blockIdx.z;
  int tid = threadIdx.x;
  int lane = tid & 63, wid = tid >> 6;
  int l15 = lane & 15, lg = lane >> 4;
  int ob = blockIdx.y * 64 + (wid >> 1) * 32;
  int nbase = blockIdx.x * 64 + (wid & 1) * 32;
  const short* aptr = wpm + (size_t)(ob + l15) * CH + lg * 8;
  const short* bptr = ao + ((size_t)b * NPIX + nbase + l15) * CH + lg * 8;
  f32x4 acc[2][2];
  #pragma unroll
  for (int mi = 0; mi < 2; ++mi)
    #pragma unroll
    for (int ni = 0; ni < 2; ++ni) acc[mi][ni] = (f32x4){0.f, 0.f, 0.f, 0.f};
  #pragma unroll 4
  for (int kk = 0; kk < CH; kk += 32) {
    bf16x8 a0 = *reinterpret_cast<const bf16x8*>(aptr + kk);
    bf16x8 a1 = *reinterpret_cast<const bf16x8*>(aptr + 16 * CH + kk);
    bf16x8 b0 = *reinterpret_cast<const bf16x8*>(bptr + kk);
    bf16x8 b1 = *reinterpret_cast<const bf16x8*>(bptr + 16 * CH + kk);
    acc[0][0] = MFMA(a0, b0, acc[0][0], 0, 0, 0);
    acc[0][1] = MFMA(a0, b1, acc[0][1], 0, 0, 0);
    acc[1][0] = MFMA(a1, b0, acc[1][0], 0, 0, 0);
    acc[1][1] = MFMA(a1, b1, acc[1][1], 0, 0, 0);
  }
  #pragma unroll
  for (int mi = 0; mi < 2; ++mi) {
    int oo = ob + mi * 16 + lg * 4;
    #pragma unroll
    for (int ni = 0; ni < 2; ++ni) {
      int nn = nbase + ni * 16 + l15;
      #pragma unroll
      for (int r = 0; r < 4; ++r) {
        size_t idx = ((size_t)b * CH + oo + r) * NPIX + nn;
        out[idx] = acc[mi][ni][r] + pb[oo + r] + x[idx];
      }
    }
  }
}

extern "C" void kernel_launch(void* const* d_in, const int* in_sizes, int n_in,
                              void* d_out, int out_size, void* d_ws, size_t ws_size,
                              hipStream_t stream) {
  const float* x  = (const float*)d_in[0];
  const float* nw = (const float*)d_in[1];
  const float* nb = (const float*)d_in[2];
  const float* qw = (const float*)d_in[3];
  const float* qb = (const float*)d_in[4];
  const float* kw = (const float*)d_in[5];
  const float* kb = (const float*)d_in[6];
  const float* vw = (const float*)d_in[7];
  const float* vb = (const float*)d_in[8];
  const float* pw = (const float*)d_in[9];
  const float* pb = (const float*)d_in[10];
  char* ws = (char*)d_ws;
  short* wstack = (short*)(ws);                    // 1,572,864
  short* wp     = (short*)(ws + 1572864);          //   524,288
  short* hT     = (short*)(ws + 2101248);          // 16,777,216
  short* qT     = (short*)(ws + 18878464);         // 16,777,216
  short* kT     = (short*)(ws + 35655680);         // 16,777,216
  short* vC     = (short*)(ws + 52432896);         // 16,777,216 (end 69,210,112)
  short* ao     = hT;                              // hT dead after qkv
  float* out = (float*)d_out;

  hipFuncSetAttribute((const void*)flash_kernel,
                      hipFuncAttributeMaxDynamicSharedMemorySize, DYN_LDS);

  wconv_kernel<<<1024, 256, 0, stream>>>(qw, kw, vw, pw, wstack, wp);
  gn_kernel<<<128, 256, 0, stream>>>(x, nw, nb, hT);
  qkv_kernel<<<dim3(64, 24, NB), 256, 0, stream>>>(wstack, hT, qb, kb, vb, qT, kT, vC);
  flash_kernel<<<dim3(128, NB), 256, DYN_LDS, stream>>>(qT, kT, vC, ao);
  proj_kernel<<<dim3(64, 8, NB), 256, 0, stream>>>(wp, ao, x, pb, out);
}

// Round 8
// 574.075 us; speedup vs baseline: 1.2796x; 1.2796x over previous
//
#include <hip/hip_runtime.h>

#define NB 4
#define CH 512
#define NPIX 4096
#define GSZ 16
#define KVB 32
#define NT (NPIX / KVB)          // 128 kv tiles
#define DYN_LDS 132096           // 64K K dbuf + 64K V dbuf + 1K scalars

typedef __attribute__((ext_vector_type(8))) short bf16x8;
typedef __attribute__((ext_vector_type(4))) short bf16x4;
typedef __attribute__((ext_vector_type(4))) float f32x4;

#define MFMA __builtin_amdgcn_mfma_f32_16x16x32_bf16

// 16x16x16 bf16 MFMA (K=16): A,B = 2 VGPRs (4 bf16), C/D = 4 VGPRs.
static __device__ __forceinline__ f32x4 mfma16(bf16x4 a, bf16x4 b, f32x4 c) {
  asm("v_mfma_f32_16x16x16_bf16 %0, %1, %2, %0" : "+v"(c) : "v"(a), "v"(b));
  return c;
}

static __device__ __forceinline__ short f2bf(float f) {
  unsigned u = __builtin_bit_cast(unsigned, f);
  u += 0x7fffu + ((u >> 16) & 1u);
  return (short)(u >> 16);
}

static __device__ __forceinline__ float bperm_f(int srclane, float v) {
  int r = __builtin_amdgcn_ds_bpermute(srclane << 2, __builtin_bit_cast(int, v));
  return __builtin_bit_cast(float, r);
}

typedef __attribute__((address_space(1))) unsigned glob_u32;
typedef __attribute__((address_space(3))) unsigned lds_u32;
static __device__ __forceinline__ void gl_lds16(const void* g, void* l) {
  __builtin_amdgcn_global_load_lds((const glob_u32*)g, (lds_u32*)l, 16, 0, 0);
}

// ---------------- kernel 1: weights fp32 -> bf16 (q,k,v stacked; proj separate)
__global__ __launch_bounds__(256) void wconv_kernel(
    const float* __restrict__ qw, const float* __restrict__ kw,
    const float* __restrict__ vw, const float* __restrict__ pw,
    short* __restrict__ wstack, short* __restrict__ wp) {
  int idx = (blockIdx.x * 256 + threadIdx.x) * 4;
  int mat = idx >> 18;
  int off = idx & 262143;
  const float* src = (mat == 0) ? qw : (mat == 1) ? kw : (mat == 2) ? vw : pw;
  short* dst = (mat < 3) ? (wstack + (size_t)mat * 262144) : wp;
  float4 v = *reinterpret_cast<const float4*>(src + off);
  bf16x4 o;
  o[0] = f2bf(v.x); o[1] = f2bf(v.y); o[2] = f2bf(v.z); o[3] = f2bf(v.w);
  *reinterpret_cast<bf16x4*>(dst + off) = o;
}

// ---------------- kernel 2: GroupNorm + bf16 + transpose -> hT [B][N][C]
// grid 256: two blocks per (b,g); stats redundant, normalize split by half.
__global__ __launch_bounds__(256) void gn_kernel(
    const float* __restrict__ x, const float* __restrict__ nw,
    const float* __restrict__ nb, short* __restrict__ hT) {
  int pairid = blockIdx.x >> 1, half = blockIdx.x & 1;
  int b = pairid >> 5, g = pairid & 31;
  int tid = threadIdx.x;
  const float* base = x + (size_t)(b * CH + g * GSZ) * NPIX;
  const float4* b4 = reinterpret_cast<const float4*>(base);
  float s = 0.f, s2 = 0.f;
  for (int i = tid; i < GSZ * NPIX / 4; i += 256) {
    float4 v = b4[i];
    s += v.x + v.y + v.z + v.w;
    s2 += v.x * v.x + v.y * v.y + v.z * v.z + v.w * v.w;
  }
  #pragma unroll
  for (int m = 1; m < 64; m <<= 1) { s += __shfl_xor(s, m); s2 += __shfl_xor(s2, m); }
  __shared__ float red[8];
  if ((tid & 63) == 0) { red[(tid >> 6) * 2] = s; red[(tid >> 6) * 2 + 1] = s2; }
  __syncthreads();
  s = red[0] + red[2] + red[4] + red[6];
  s2 = red[1] + red[3] + red[5] + red[7];
  float mean = s * (1.f / 65536.f);
  float var = s2 * (1.f / 65536.f) - mean * mean;
  float rstd = rsqrtf(var + 1e-5f);
  int c = tid >> 4, nq = tid & 15;
  float wch = nw[g * GSZ + c] * rstd;
  float bch = nb[g * GSZ + c] - mean * wch;
  __shared__ short lt[GSZ][264];
  short* outb = hT + (size_t)b * NPIX * CH + g * GSZ;
  const float* srcc = base + (size_t)c * NPIX + nq * 16;
  for (int chunk = half * 8; chunk < half * 8 + 8; ++chunk) {
    const float4* sp = reinterpret_cast<const float4*>(srcc + chunk * 256);
    float4 v0 = sp[0], v1 = sp[1], v2 = sp[2], v3 = sp[3];
    bf16x8 w0, w1;
    w0[0] = f2bf(v0.x * wch + bch); w0[1] = f2bf(v0.y * wch + bch);
    w0[2] = f2bf(v0.z * wch + bch); w0[3] = f2bf(v0.w * wch + bch);
    w0[4] = f2bf(v1.x * wch + bch); w0[5] = f2bf(v1.y * wch + bch);
    w0[6] = f2bf(v1.z * wch + bch); w0[7] = f2bf(v1.w * wch + bch);
    w1[0] = f2bf(v2.x * wch + bch); w1[1] = f2bf(v2.y * wch + bch);
    w1[2] = f2bf(v2.z * wch + bch); w1[3] = f2bf(v2.w * wch + bch);
    w1[4] = f2bf(v3.x * wch + bch); w1[5] = f2bf(v3.y * wch + bch);
    w1[6] = f2bf(v3.z * wch + bch); w1[7] = f2bf(v3.w * wch + bch);
    *reinterpret_cast<bf16x8*>(&lt[c][nq * 16]) = w0;
    *reinterpret_cast<bf16x8*>(&lt[c][nq * 16 + 8]) = w1;
    __syncthreads();
    bf16x8 o0, o1;
    #pragma unroll
    for (int cc = 0; cc < 8; ++cc) o0[cc] = lt[cc][tid];
    #pragma unroll
    for (int cc = 0; cc < 8; ++cc) o1[cc] = lt[cc + 8][tid];
    short* orow = outb + (size_t)(chunk * 256 + tid) * CH;
    *reinterpret_cast<bf16x8*>(orow) = o0;
    *reinterpret_cast<bf16x8*>(orow + 8) = o1;
    __syncthreads();
  }
}

// ---------------- kernel 3: QKV GEMM (stacked M=1536) from hT token-major
// q output is pre-scaled by 512^-0.5
__global__ __launch_bounds__(256) void qkv_kernel(
    const short* __restrict__ wstack, const short* __restrict__ hT,
    const float* __restrict__ qb, const float* __restrict__ kb,
    const float* __restrict__ vb,
    short* __restrict__ qT, short* __restrict__ kT, short* __restrict__ vC) {
  int b = blockIdx.z;
  int tid = threadIdx.x;
  int lane = tid & 63, wid = tid >> 6;
  int l15 = lane & 15, lg = lane >> 4;
  int ob = blockIdx.y * 64 + (wid >> 1) * 32;
  int nbase = blockIdx.x * 64 + (wid & 1) * 32;
  const short* aptr = wstack + (size_t)(ob + l15) * CH + lg * 8;
  const short* bptr = hT + ((size_t)b * NPIX + nbase + l15) * CH + lg * 8;
  f32x4 acc[2][2];
  #pragma unroll
  for (int mi = 0; mi < 2; ++mi)
    #pragma unroll
    for (int ni = 0; ni < 2; ++ni) acc[mi][ni] = (f32x4){0.f, 0.f, 0.f, 0.f};
  #pragma unroll 4
  for (int kk = 0; kk < CH; kk += 32) {
    bf16x8 a0 = *reinterpret_cast<const bf16x8*>(aptr + kk);
    bf16x8 a1 = *reinterpret_cast<const bf16x8*>(aptr + 16 * CH + kk);
    bf16x8 b0 = *reinterpret_cast<const bf16x8*>(bptr + kk);
    bf16x8 b1 = *reinterpret_cast<const bf16x8*>(bptr + 16 * CH + kk);
    acc[0][0] = MFMA(a0, b0, acc[0][0], 0, 0, 0);
    acc[0][1] = MFMA(a0, b1, acc[0][1], 0, 0, 0);
    acc[1][0] = MFMA(a1, b0, acc[1][0], 0, 0, 0);
    acc[1][1] = MFMA(a1, b1, acc[1][1], 0, 0, 0);
  }
  int oglob = blockIdx.y * 64;
  #pragma unroll
  for (int mi = 0; mi < 2; ++mi) {
    int oo = ob + mi * 16 + lg * 4;
    #pragma unroll
    for (int ni = 0; ni < 2; ++ni) {
      int nn = nbase + ni * 16 + l15;
      f32x4 a = acc[mi][ni];
      if (oglob < 1024) {
        const float* bias = (oglob < 512) ? qb : kb;
        short* dstm = (oglob < 512) ? qT : kT;
        float sc = (oglob < 512) ? 0.044194173824159216f : 1.0f;
        int ol = oo & 511;
        bf16x4 pk;
        #pragma unroll
        for (int r = 0; r < 4; ++r) pk[r] = f2bf((a[r] + bias[ol + r]) * sc);
        *reinterpret_cast<bf16x4*>(dstm + ((size_t)b * NPIX + nn) * CH + ol) = pk;
      } else {
        int ov = oo - 1024;
        short* dstv = vC + ((size_t)b * CH + ov) * NPIX + nn;
        #pragma unroll
        for (int r = 0; r < 4; ++r) dstv[(size_t)r * NPIX] = f2bf(a[r] + vb[ov + r]);
      }
    }
  }
}

// ---------------- kernel 4: flash attention, 8 waves. Each wave = independent
// online-softmax flash over its kv-half (16 kv of the 32-tile), 16 q rows,
// FULL d (O = 128 VGPR). P stays in registers (S^T C-layout == mfma16 A-layout).
// One barrier per iteration. Pair-merge in epilogue via LDS.
// qT(pre-scaled),kT: [B][N][C] bf16; vC: [B][C][N] bf16; ao: [B][N][C] bf16
__global__ __launch_bounds__(512, 2) void flash_kernel(
    const short* __restrict__ qT, const short* __restrict__ kT,
    const short* __restrict__ vC, short* __restrict__ ao) {
  extern __shared__ char smem[];
  char* kbuf = smem;                         // [2][32][1024B] K (XOR-swz)
  char* vbuf = smem + 65536;                 // [2][512][64B]  V (XOR-swz)
  float* sm = (float*)(smem + 131072);       // [8][16] running max
  float* sl = (float*)(smem + 131072 + 512); // [8][16] running sum

  // XCD-aware swizzle: 32 consecutive logical blocks per XCD.
  int lin = blockIdx.y * 64 + blockIdx.x;    // 0..255
  int sw = (lin & 7) * 32 + (lin >> 3);      // bijective (256 % 8 == 0)
  int qb = sw & 63, b = sw >> 6;

  int tid = threadIdx.x;
  int lane = tid & 63, w = tid >> 6;         // 8 waves
  int p = w >> 1, h = w & 1;                 // pair, kv-half
  int l15 = lane & 15, lg = lane >> 4;
  int qrow = qb * 64 + p * 16;

  const short* qptr = qT + ((size_t)b * NPIX + qrow + l15) * CH + lg * 8;
  bf16x8 qf[16];
  #pragma unroll
  for (int ks = 0; ks < 16; ++ks) qf[ks] = *reinterpret_cast<const bf16x8*>(qptr + ks * 32);

  f32x4 oacc[32];                            // O_half[16q][512d]
  #pragma unroll
  for (int i = 0; i < 32; ++i) oacc[i] = (f32x4){0.f, 0.f, 0.f, 0.f};
  float mrow = -INFINITY, lrow = 0.f;        // per-lane: q = l15

  const short* kTb = kT + (size_t)b * NPIX * CH;
  const short* vCb = vC + (size_t)b * CH * NPIX;
  const int swz = (l15 & 7) << 4;
  const int vx = (l15 >> 1) & 3;             // V chunk-swizzle key

  auto stage = [&](int buf, int t) {
    int m0 = t * KVB;
    char* kd = kbuf + buf * 32768;
    char* vd = vbuf + buf * 32768;
    #pragma unroll
    for (int i = 0; i < 4; ++i) {            // K rows (src pre-swizzled)
      int r = w * 4 + i;
      const short* src = kTb + (size_t)(m0 + r) * CH + ((lane ^ (r & 7)) * 8);
      gl_lds16(src, kd + r * 1024);
    }
    #pragma unroll
    for (int i = 0; i < 4; ++i) {            // V chunks (src pre-swizzled)
      int j = w * 4 + i;
      int ch = j * 16 + (lane >> 2);
      const short* src = vCb + (size_t)ch * NPIX + m0 +
                         (((lane & 3) ^ ((lane >> 3) & 3)) * 8);
      gl_lds16(src, vd + j * 1024);
    }
  };

  stage(0, 0);
  asm volatile("s_waitcnt vmcnt(0)" ::: "memory");
  __syncthreads();

  int cur = 0;
  for (int t = 0; t < NT; ++t) {
    const char* kb_ = kbuf + cur * 32768;
    const char* vb_ = vbuf + cur * 32768;
    // ---- 0. issue next-tile staging; drained only at end barrier
    if (t + 1 < NT) stage(cur ^ 1, t + 1);
    // ---- 1. swapped QK: S^T[16kv(h), 16q], 2 interleaved chains
    f32x4 sa = (f32x4){0.f, 0.f, 0.f, 0.f};
    f32x4 sb = (f32x4){0.f, 0.f, 0.f, 0.f};
    __builtin_amdgcn_s_setprio(1);
    #pragma unroll
    for (int cs = 0; cs < 16; cs += 2) {
      bf16x8 kf0 = *reinterpret_cast<const bf16x8*>(
          kb_ + (h * 16 + l15) * 1024 + ((cs * 64 + lg * 16) ^ swz));
      bf16x8 kf1 = *reinterpret_cast<const bf16x8*>(
          kb_ + (h * 16 + l15) * 1024 + (((cs + 1) * 64 + lg * 16) ^ swz));
      sa = MFMA(kf0, qf[cs], sa, 0, 0, 0);
      sb = MFMA(kf1, qf[cs + 1], sb, 0, 0, 0);
    }
    __builtin_amdgcn_s_setprio(0);
    f32x4 st = sa + sb;
    // ---- 2. own-half online softmax (per-lane q = l15)
    float tmax = fmaxf(fmaxf(st[0], st[1]), fmaxf(st[2], st[3]));
    tmax = fmaxf(tmax, __shfl_xor(tmax, 16));
    tmax = fmaxf(tmax, __shfl_xor(tmax, 32));
    float mnew = fmaxf(mrow, tmax);
    float alpha = __expf(mrow - mnew);
    float p0 = __expf(st[0] - mnew), p1 = __expf(st[1] - mnew);
    float p2 = __expf(st[2] - mnew), p3 = __expf(st[3] - mnew);
    float psum = (p0 + p1) + (p2 + p3);
    psum += __shfl_xor(psum, 16);
    psum += __shfl_xor(psum, 32);
    lrow = lrow * alpha + psum;
    bool nochg = (mnew == mrow);
    mrow = mnew;
    // ---- 3. rescale O by alpha (skip when max unchanged: alpha == 1)
    if (!__all((int)nochg)) {
      float a4[4];
      #pragma unroll
      for (int r = 0; r < 4; ++r) a4[r] = bperm_f(lg * 4 + r, alpha);
      #pragma unroll
      for (int j = 0; j < 32; ++j) {
        oacc[j][0] *= a4[0]; oacc[j][1] *= a4[1];
        oacc[j][2] *= a4[2]; oacc[j][3] *= a4[3];
      }
    }
    // ---- 4. P in-register (A-frag of mfma16 == S^T C-layout), PV over own half
    bf16x4 pk;
    pk[0] = f2bf(p0); pk[1] = f2bf(p1); pk[2] = f2bf(p2); pk[3] = f2bf(p3);
    __builtin_amdgcn_s_setprio(1);
    #pragma unroll
    for (int j = 0; j < 32; ++j) {
      // V B-frag: d = j*16+l15, kv = h*16 + lg*4..+4 (8B, deswizzled chunk)
      int vaddr = (j * 16 + l15) * 64 +
                  ((((h << 1) | (lg >> 1)) ^ vx) << 4) + ((lg & 1) << 3);
      bf16x4 vf = *reinterpret_cast<const bf16x4*>(vb_ + vaddr);
      oacc[j] = mfma16(pk, vf, oacc[j]);
    }
    __builtin_amdgcn_s_setprio(0);
    // ---- 5. single barrier: staging done + all buffer reads drained
    asm volatile("s_waitcnt vmcnt(0) lgkmcnt(0)" ::: "memory");
    __builtin_amdgcn_s_barrier();
    __builtin_amdgcn_sched_barrier(0);
    cur ^= 1;
  }

  // ---- epilogue: pair-merge (two-partition flash combine) via freed LDS
  if (lane < 16) { sm[w * 16 + l15] = mrow; sl[w * 16 + l15] = lrow; }
  if (!(h & 1)) {                            // even wave deposits O as [d][q] f32
    float* ob = (float*)(smem + p * 32768);
    #pragma unroll
    for (int j = 0; j < 32; ++j)
      *reinterpret_cast<f32x4*>(ob + (j * 16 + l15) * 16 + lg * 4) = oacc[j];
  }
  __syncthreads();
  if (h & 1) {                               // odd wave combines + writes out
    float mo = sm[(w ^ 1) * 16 + l15], lo = sl[(w ^ 1) * 16 + l15];
    float mS = fmaxf(mrow, mo);
    float co = __expf(mo - mS), cw = __expf(mrow - mS);
    float rin = 1.f / (cw * lrow + co * lo);
    float co4[4], cw4[4];
    #pragma unroll
    for (int r = 0; r < 4; ++r) {
      co4[r] = bperm_f(lg * 4 + r, co * rin);
      cw4[r] = bperm_f(lg * 4 + r, cw * rin);
    }
    float* ob = (float*)(smem + p * 32768);
    short* aob = ao + ((size_t)b * NPIX + qrow) * CH;
    #pragma unroll
    for (int j = 0; j < 32; ++j) {
      f32x4 po = *reinterpret_cast<const f32x4*>(ob + (j * 16 + l15) * 16 + lg * 4);
      #pragma unroll
      for (int r = 0; r < 4; ++r) {
        float v = cw4[r] * oacc[j][r] + co4[r] * po[r];
        aob[(size_t)(lg * 4 + r) * CH + j * 16 + l15] = f2bf(v);
      }
    }
  }
}

// ---------------- kernel 5: proj GEMM + bias + residual (fp32 out)
__global__ __launch_bounds__(256) void proj_kernel(
    const short* __restrict__ wpm, const short* __restrict__ ao,
    const float* __restrict__ x, const float* __restrict__ pb,
    float* __restrict__ out) {
  int b = blockIdx.z;
  int tid = threadIdx.x;
  int lane = tid & 63, wid = tid >> 6;
  int l15 = lane & 15, lg = lane >> 4;
  int ob = blockIdx.y * 64 + (wid >> 1) * 32;
  int nbase = blockIdx.x * 64 + (wid & 1) * 32;
  const short* aptr = wpm + (size_t)(ob + l15) * CH + lg * 8;
  const short* bptr = ao + ((size_t)b * NPIX + nbase + l15) * CH + lg * 8;
  f32x4 acc[2][2];
  #pragma unroll
  for (int mi = 0; mi < 2; ++mi)
    #pragma unroll
    for (int ni = 0; ni < 2; ++ni) acc[mi][ni] = (f32x4){0.f, 0.f, 0.f, 0.f};
  #pragma unroll 4
  for (int kk = 0; kk < CH; kk += 32) {
    bf16x8 a0 = *reinterpret_cast<const bf16x8*>(aptr + kk);
    bf16x8 a1 = *reinterpret_cast<const bf16x8*>(aptr + 16 * CH + kk);
    bf16x8 b0 = *reinterpret_cast<const bf16x8*>(bptr + kk);
    bf16x8 b1 = *reinterpret_cast<const bf16x8*>(bptr + 16 * CH + kk);
    acc[0][0] = MFMA(a0, b0, acc[0][0], 0, 0, 0);
    acc[0][1] = MFMA(a0, b1, acc[0][1], 0, 0, 0);
    acc[1][0] = MFMA(a1, b0, acc[1][0], 0, 0, 0);
    acc[1][1] = MFMA(a1, b1, acc[1][1], 0, 0, 0);
  }
  #pragma unroll
  for (int mi = 0; mi < 2; ++mi) {
    int oo = ob + mi * 16 + lg * 4;
    #pragma unroll
    for (int ni = 0; ni < 2; ++ni) {
      int nn = nbase + ni * 16 + l15;
      #pragma unroll
      for (int r = 0; r < 4; ++r) {
        size_t idx = ((size_t)b * CH + oo + r) * NPIX + nn;
        out[idx] = acc[mi][ni][r] + pb[oo + r] + x[idx];
      }
    }
  }
}

extern "C" void kernel_launch(void* const* d_in, const int* in_sizes, int n_in,
                              void* d_out, int out_size, void* d_ws, size_t ws_size,
                              hipStream_t stream) {
  const float* x  = (const float*)d_in[0];
  const float* nw = (const float*)d_in[1];
  const float* nb = (const float*)d_in[2];
  const float* qw = (const float*)d_in[3];
  const float* qb = (const float*)d_in[4];
  const float* kw = (const float*)d_in[5];
  const float* kb = (const float*)d_in[6];
  const float* vw = (const float*)d_in[7];
  const float* vb = (const float*)d_in[8];
  const float* pw = (const float*)d_in[9];
  const float* pb = (const float*)d_in[10];
  char* ws = (char*)d_ws;
  short* wstack = (short*)(ws);                    // 1,572,864
  short* wp     = (short*)(ws + 1572864);          //   524,288
  short* hT     = (short*)(ws + 2101248);          // 16,777,216
  short* qT     = (short*)(ws + 18878464);         // 16,777,216
  short* kT     = (short*)(ws + 35655680);         // 16,777,216
  short* vC     = (short*)(ws + 52432896);         // 16,777,216 (end 69,210,112)
  short* ao     = hT;                              // hT dead after qkv
  float* out = (float*)d_out;

  hipFuncSetAttribute((const void*)flash_kernel,
                      hipFuncAttributeMaxDynamicSharedMemorySize, DYN_LDS);

  wconv_kernel<<<1024, 256, 0, stream>>>(qw, kw, vw, pw, wstack, wp);
  gn_kernel<<<256, 256, 0, stream>>>(x, nw, nb, hT);
  qkv_kernel<<<dim3(64, 24, NB), 256, 0, stream>>>(wstack, hT, qb, kb, vb, qT, kT, vC);
  flash_kernel<<<dim3(64, NB), 512, DYN_LDS, stream>>>(qT, kT, vC, ao);
  proj_kernel<<<dim3(64, 8, NB), 256, 0, stream>>>(wp, ao, x, pb, out);
}

// Round 9
// 471.646 us; speedup vs baseline: 1.5575x; 1.2172x over previous
//
#include <hip/hip_runtime.h>

#define NB 4
#define CH 512
#define NPIX 4096
#define GSZ 16
#define KVB 32
#define NT (NPIX / KVB)          // 128 kv tiles
#define DYN_LDS 136192           // 64K K dbuf + 64K V dbuf + 4K P + 1K exch
#define QKV_LDS 65536            // 2 x (128x64 A + 128x64 B) bf16

typedef __attribute__((ext_vector_type(8))) short bf16x8;
typedef __attribute__((ext_vector_type(4))) short bf16x4;
typedef __attribute__((ext_vector_type(4))) float f32x4;

#define MFMA __builtin_amdgcn_mfma_f32_16x16x32_bf16

static __device__ __forceinline__ short f2bf(float f) {
  unsigned u = __builtin_bit_cast(unsigned, f);
  u += 0x7fffu + ((u >> 16) & 1u);
  return (short)(u >> 16);
}

static __device__ __forceinline__ float bperm_f(int srclane, float v) {
  int r = __builtin_amdgcn_ds_bpermute(srclane << 2, __builtin_bit_cast(int, v));
  return __builtin_bit_cast(float, r);
}

typedef __attribute__((address_space(1))) unsigned glob_u32;
typedef __attribute__((address_space(3))) unsigned lds_u32;
static __device__ __forceinline__ void gl_lds16(const void* g, void* l) {
  __builtin_amdgcn_global_load_lds((const glob_u32*)g, (lds_u32*)l, 16, 0, 0);
}

// ---------------- kernel 1: weights fp32 -> bf16 (q,k,v stacked; proj separate)
__global__ __launch_bounds__(256) void wconv_kernel(
    const float* __restrict__ qw, const float* __restrict__ kw,
    const float* __restrict__ vw, const float* __restrict__ pw,
    short* __restrict__ wstack, short* __restrict__ wp) {
  int idx = (blockIdx.x * 256 + threadIdx.x) * 4;
  int mat = idx >> 18;
  int off = idx & 262143;
  const float* src = (mat == 0) ? qw : (mat == 1) ? kw : (mat == 2) ? vw : pw;
  short* dst = (mat < 3) ? (wstack + (size_t)mat * 262144) : wp;
  float4 v = *reinterpret_cast<const float4*>(src + off);
  bf16x4 o;
  o[0] = f2bf(v.x); o[1] = f2bf(v.y); o[2] = f2bf(v.z); o[3] = f2bf(v.w);
  *reinterpret_cast<bf16x4*>(dst + off) = o;
}

// ---------------- kernel 2: GroupNorm + bf16 + transpose -> hT [B][N][C]
// grid 256: two blocks per (b,g); stats redundant, normalize split by half.
__global__ __launch_bounds__(256) void gn_kernel(
    const float* __restrict__ x, const float* __restrict__ nw,
    const float* __restrict__ nb, short* __restrict__ hT) {
  int pairid = blockIdx.x >> 1, half = blockIdx.x & 1;
  int b = pairid >> 5, g = pairid & 31;
  int tid = threadIdx.x;
  const float* base = x + (size_t)(b * CH + g * GSZ) * NPIX;
  const float4* b4 = reinterpret_cast<const float4*>(base);
  float s = 0.f, s2 = 0.f;
  for (int i = tid; i < GSZ * NPIX / 4; i += 256) {
    float4 v = b4[i];
    s += v.x + v.y + v.z + v.w;
    s2 += v.x * v.x + v.y * v.y + v.z * v.z + v.w * v.w;
  }
  #pragma unroll
  for (int m = 1; m < 64; m <<= 1) { s += __shfl_xor(s, m); s2 += __shfl_xor(s2, m); }
  __shared__ float red[8];
  if ((tid & 63) == 0) { red[(tid >> 6) * 2] = s; red[(tid >> 6) * 2 + 1] = s2; }
  __syncthreads();
  s = red[0] + red[2] + red[4] + red[6];
  s2 = red[1] + red[3] + red[5] + red[7];
  float mean = s * (1.f / 65536.f);
  float var = s2 * (1.f / 65536.f) - mean * mean;
  float rstd = rsqrtf(var + 1e-5f);
  int c = tid >> 4, nq = tid & 15;
  float wch = nw[g * GSZ + c] * rstd;
  float bch = nb[g * GSZ + c] - mean * wch;
  __shared__ short lt[GSZ][264];
  short* outb = hT + (size_t)b * NPIX * CH + g * GSZ;
  const float* srcc = base + (size_t)c * NPIX + nq * 16;
  for (int chunk = half * 8; chunk < half * 8 + 8; ++chunk) {
    const float4* sp = reinterpret_cast<const float4*>(srcc + chunk * 256);
    float4 v0 = sp[0], v1 = sp[1], v2 = sp[2], v3 = sp[3];
    bf16x8 w0, w1;
    w0[0] = f2bf(v0.x * wch + bch); w0[1] = f2bf(v0.y * wch + bch);
    w0[2] = f2bf(v0.z * wch + bch); w0[3] = f2bf(v0.w * wch + bch);
    w0[4] = f2bf(v1.x * wch + bch); w0[5] = f2bf(v1.y * wch + bch);
    w0[6] = f2bf(v1.z * wch + bch); w0[7] = f2bf(v1.w * wch + bch);
    w1[0] = f2bf(v2.x * wch + bch); w1[1] = f2bf(v2.y * wch + bch);
    w1[2] = f2bf(v2.z * wch + bch); w1[3] = f2bf(v2.w * wch + bch);
    w1[4] = f2bf(v3.x * wch + bch); w1[5] = f2bf(v3.y * wch + bch);
    w1[6] = f2bf(v3.z * wch + bch); w1[7] = f2bf(v3.w * wch + bch);
    *reinterpret_cast<bf16x8*>(&lt[c][nq * 16]) = w0;
    *reinterpret_cast<bf16x8*>(&lt[c][nq * 16 + 8]) = w1;
    __syncthreads();
    bf16x8 o0, o1;
    #pragma unroll
    for (int cc = 0; cc < 8; ++cc) o0[cc] = lt[cc][tid];
    #pragma unroll
    for (int cc = 0; cc < 8; ++cc) o1[cc] = lt[cc + 8][tid];
    short* orow = outb + (size_t)(chunk * 256 + tid) * CH;
    *reinterpret_cast<bf16x8*>(orow) = o0;
    *reinterpret_cast<bf16x8*>(orow + 8) = o1;
    __syncthreads();
  }
}

// ---------------- kernel 3: QKV GEMM, m97-style 128x128xBK64 double-buffered
// LDS staging via global_load_lds + XOR swizzle. M=1536 stacked [q|k|v].
// q output pre-scaled by 512^-0.5.
__global__ __launch_bounds__(256) void qkv_kernel(
    const short* __restrict__ wstack, const short* __restrict__ hT,
    const float* __restrict__ qb, const float* __restrict__ kb,
    const float* __restrict__ vb,
    short* __restrict__ qT, short* __restrict__ kT, short* __restrict__ vC) {
  extern __shared__ char qsm[];
  char* abuf = qsm;                 // [2][128][128B] weights tile
  char* bbuf = qsm + 32768;         // [2][128][128B] hT tile

  int b = blockIdx.z;
  int by = blockIdx.y;              // 0..11 (q 0-3, k 4-7, v 8-11)
  int nbase = blockIdx.x * 128;
  int tid = threadIdx.x;
  int lane = tid & 63, wid = tid >> 6;
  int l15 = lane & 15, lg = lane >> 4;
  int wr = wid >> 1, wc = wid & 1;  // wave sub-tile 64x64 at (wr*64, wc*64)

  const short* arows = wstack + (size_t)by * 128 * CH;
  const short* brows = hT + ((size_t)b * NPIX + nbase) * CH;

  // stage one BK=64 slice of A and B into buffer `buf` (src pre-swizzled)
  auto stage = [&](int buf, int kidx) {
    char* ad = abuf + buf * 16384;
    char* bd = bbuf + buf * 16384;
    #pragma unroll
    for (int i = 0; i < 4; ++i) {
      int off = i * 4096 + tid * 16;
      int row = off >> 7;
      int c16 = (off >> 4) & 7;
      int gchunk = (c16 ^ (row & 7)) * 8;
      gl_lds16(arows + (size_t)row * CH + kidx * 64 + gchunk, ad + off);
      gl_lds16(brows + (size_t)row * CH + kidx * 64 + gchunk, bd + off);
    }
  };

  f32x4 acc[4][4];
  #pragma unroll
  for (int mi = 0; mi < 4; ++mi)
    #pragma unroll
    for (int ni = 0; ni < 4; ++ni) acc[mi][ni] = (f32x4){0.f, 0.f, 0.f, 0.f};

  stage(0, 0);
  __syncthreads();

  int cur = 0;
  for (int kt = 0; kt < 8; ++kt) {
    if (kt + 1 < 8) stage(cur ^ 1, kt + 1);
    const char* ab = abuf + cur * 16384;
    const char* bb = bbuf + cur * 16384;
    #pragma unroll
    for (int ks = 0; ks < 2; ++ks) {
      bf16x8 af[4], bf[4];
      #pragma unroll
      for (int mi = 0; mi < 4; ++mi) {
        int row = wr * 64 + mi * 16 + l15;
        af[mi] = *reinterpret_cast<const bf16x8*>(
            ab + row * 128 + (((ks * 4 + lg) ^ (row & 7)) << 4));
      }
      #pragma unroll
      for (int ni = 0; ni < 4; ++ni) {
        int row = wc * 64 + ni * 16 + l15;
        bf[ni] = *reinterpret_cast<const bf16x8*>(
            bb + row * 128 + (((ks * 4 + lg) ^ (row & 7)) << 4));
      }
      #pragma unroll
      for (int mi = 0; mi < 4; ++mi)
        #pragma unroll
        for (int ni = 0; ni < 4; ++ni)
          acc[mi][ni] = MFMA(af[mi], bf[ni], acc[mi][ni], 0, 0, 0);
    }
    __syncthreads();
    cur ^= 1;
  }

  int oglob = by * 128;
  #pragma unroll
  for (int mi = 0; mi < 4; ++mi) {
    int oo = oglob + wr * 64 + mi * 16 + lg * 4;
    #pragma unroll
    for (int ni = 0; ni < 4; ++ni) {
      int nn = nbase + wc * 64 + ni * 16 + l15;
      f32x4 a = acc[mi][ni];
      if (oglob < 1024) {
        const float* bias = (oglob < 512) ? qb : kb;
        short* dstm = (oglob < 512) ? qT : kT;
        float sc = (oglob < 512) ? 0.044194173824159216f : 1.0f;
        int ol = oo & 511;
        bf16x4 pk;
        #pragma unroll
        for (int r = 0; r < 4; ++r) pk[r] = f2bf((a[r] + bias[ol + r]) * sc);
        *reinterpret_cast<bf16x4*>(dstm + ((size_t)b * NPIX + nn) * CH + ol) = pk;
      } else {
        int ov = oo - 1024;
        short* dstv = vC + ((size_t)b * CH + ov) * NPIX + nn;
        #pragma unroll
        for (int r = 0; r < 4; ++r) dstv[(size_t)r * NPIX] = f2bf(a[r] + vb[ov + r]);
      }
    }
  }
}

// ---------------- kernel 4: flash attention (R6-best), 8 waves, kv-split
// pairs, swapped QK^T (per-lane softmax), PV delayed one iter, pipelined.
// qT(pre-scaled),kT: [B][N][C] bf16; vC: [B][C][N] bf16; ao: [B][N][C] bf16
__global__ __launch_bounds__(512, 2) void flash_kernel(
    const short* __restrict__ qT, const short* __restrict__ kT,
    const short* __restrict__ vC, short* __restrict__ ao) {
  extern __shared__ char smem[];
  char* kbuf = smem;                         // [2][32][1024B] K (XOR-swz)
  char* vbuf = smem + 65536;                 // [2][512][64B]  V (XOR-swz)
  char* pbuf = smem + 131072;                // [4 pairs][16q][64B] P~ (XOR-swz)
  float* exch = (float*)(smem + 135168);     // [8 waves][16q][2] (m, psum)

  int lin = blockIdx.y * 64 + blockIdx.x;    // 0..255
  int sw = (lin & 7) * 32 + (lin >> 3);      // XCD swizzle (256 % 8 == 0)
  int qb = sw & 63, b = sw >> 6;

  int tid = threadIdx.x;
  int lane = tid & 63, w = tid >> 6;         // 8 waves
  int p = w >> 1, h = w & 1;                 // pair, kv/d-half
  int l15 = lane & 15, lg = lane >> 4;
  int qrow = qb * 64 + p * 16;

  const short* qptr = qT + ((size_t)b * NPIX + qrow + l15) * CH + lg * 8;
  bf16x8 qf[16];
  #pragma unroll
  for (int ks = 0; ks < 16; ++ks) qf[ks] = *reinterpret_cast<const bf16x8*>(qptr + ks * 32);

  f32x4 oacc[16];
  #pragma unroll
  for (int i = 0; i < 16; ++i) oacc[i] = (f32x4){0.f, 0.f, 0.f, 0.f};
  float mrow = -INFINITY, lrow = 0.f;        // per-lane: q = l15
  bf16x8 pa_prev;
  bf16x8 vf_prev[16];
  #pragma unroll
  for (int i = 0; i < 8; ++i) pa_prev[i] = 0;
  #pragma unroll
  for (int j = 0; j < 16; ++j)
    #pragma unroll
    for (int i = 0; i < 8; ++i) vf_prev[j][i] = 0;

  const short* kTb = kT + (size_t)b * NPIX * CH;
  const short* vCb = vC + (size_t)b * CH * NPIX;
  const int swz = (l15 & 7) << 4;
  const int vswz = ((l15 >> 1) & 3) << 4;
  const int pswz = (l15 & 3) << 4;
  char* ppair = pbuf + p * 1024;
  float* exw = exch + (w * 16 + l15) * 2;          // own slot
  float* exr = exch + ((w ^ 1) * 16 + l15) * 2;    // partner slot

  auto stage = [&](int buf, int t) {
    int m0 = t * KVB;
    char* kd = kbuf + buf * 32768;
    char* vd = vbuf + buf * 32768;
    #pragma unroll
    for (int i = 0; i < 4; ++i) {            // K rows (src pre-swizzled)
      int r = w * 4 + i;
      const short* src = kTb + (size_t)(m0 + r) * CH + ((lane ^ (r & 7)) * 8);
      gl_lds16(src, kd + r * 1024);
    }
    #pragma unroll
    for (int i = 0; i < 4; ++i) {            // V chunks (src pre-swizzled)
      int j = w * 4 + i;
      int ch = j * 16 + (lane >> 2);
      const short* src = vCb + (size_t)ch * NPIX + m0 +
                         (((lane & 3) ^ ((lane >> 3) & 3)) * 8);
      gl_lds16(src, vd + j * 1024);
    }
  };

  stage(0, 0);
  asm volatile("s_waitcnt vmcnt(0)" ::: "memory");
  __syncthreads();

  int cur = 0;
  for (int t = 0; t < NT; ++t) {
    const char* kb_ = kbuf + cur * 32768;
    const char* vb_ = vbuf + cur * 32768;
    // ---- 0. issue next-tile staging NOW; drained only at bar2 (full cover)
    if (t + 1 < NT) stage(cur ^ 1, t + 1);
    // ---- 1. swapped QK: S^T[16kv(h), 16q] = K_h * Q^T
    f32x4 st = (f32x4){0.f, 0.f, 0.f, 0.f};
    __builtin_amdgcn_s_setprio(1);
    #pragma unroll
    for (int cs = 0; cs < 16; ++cs) {
      bf16x8 kf = *reinterpret_cast<const bf16x8*>(
          kb_ + (h * 16 + l15) * 1024 + ((cs * 64 + lg * 16) ^ swz));
      st = MFMA(kf, qf[cs], st, 0, 0, 0);
    }
    __builtin_amdgcn_s_setprio(0);
    // ---- 2. own-half reduce
    float tmax = fmaxf(fmaxf(st[0], st[1]), fmaxf(st[2], st[3]));
    tmax = fmaxf(tmax, __shfl_xor(tmax, 16));
    tmax = fmaxf(tmax, __shfl_xor(tmax, 32));
    float pr[4];
    float psh;
    pr[0] = __expf(st[0] - tmax); pr[1] = __expf(st[1] - tmax);
    pr[2] = __expf(st[2] - tmax); pr[3] = __expf(st[3] - tmax);
    psh = (pr[0] + pr[1]) + (pr[2] + pr[3]);
    psh += __shfl_xor(psh, 16);
    psh += __shfl_xor(psh, 32);
    if (lane < 16) { exw[0] = tmax; exw[1] = psh; }
    // ---- bar1: LDS-only drain; staging stays in flight (no vmcnt)
    asm volatile("s_waitcnt lgkmcnt(0)" ::: "memory");
    __builtin_amdgcn_s_barrier();
    __builtin_amdgcn_sched_barrier(0);
    // ---- 3. combine with partner half
    float mo = exr[0], po = exr[1];
    float mnew = fmaxf(mrow, fmaxf(tmax, mo));
    float alpha = __expf(mrow - mnew);
    float scl = __expf(tmax - mnew);
    lrow = lrow * alpha + psh * scl + po * __expf(mo - mnew);
    mrow = mnew;
    // ---- 4. P~ = P_h * scl -> LDS
    {
      bf16x4 pk;
      pk[0] = f2bf(pr[0] * scl); pk[1] = f2bf(pr[1] * scl);
      pk[2] = f2bf(pr[2] * scl); pk[3] = f2bf(pr[3] * scl);
      *reinterpret_cast<bf16x4*>(ppair + l15 * 64 + ((h * 32 + lg * 8) ^ pswz)) = pk;
    }
    // ---- 5. PV(t-1) in registers, then rescale by alpha
    __builtin_amdgcn_s_setprio(1);
    #pragma unroll
    for (int j = 0; j < 16; ++j)
      oacc[j] = MFMA(pa_prev, vf_prev[j], oacc[j], 0, 0, 0);
    __builtin_amdgcn_s_setprio(0);
    if (!__all(alpha == 1.0f)) {
      float a4[4];
      #pragma unroll
      for (int r = 0; r < 4; ++r) a4[r] = bperm_f(lg * 4 + r, alpha);
      #pragma unroll
      for (int j = 0; j < 16; ++j) {
        oacc[j][0] *= a4[0]; oacc[j][1] *= a4[1];
        oacc[j][2] *= a4[2]; oacc[j][3] *= a4[3];
      }
    }
    // ---- 5.5 register prefetch of V(t) fragments
    #pragma unroll
    for (int j = 0; j < 16; ++j)
      vf_prev[j] = *reinterpret_cast<const bf16x8*>(
          vb_ + ((h * 16 + j) * 16 + l15) * 64 + ((lg * 16) ^ vswz));
    // ---- bar2: staged tile t+1 + P~ visible
    asm volatile("s_waitcnt vmcnt(0) lgkmcnt(0)" ::: "memory");
    __builtin_amdgcn_s_barrier();
    __builtin_amdgcn_sched_barrier(0);
    // ---- 7. P~(t) fragment for next-iter PV
    pa_prev = *reinterpret_cast<const bf16x8*>(ppair + l15 * 64 + ((lg * 16) ^ pswz));
    cur ^= 1;
  }
  // ---- final PV for last tile
  #pragma unroll
  for (int j = 0; j < 16; ++j)
    oacc[j] = MFMA(pa_prev, vf_prev[j], oacc[j], 0, 0, 0);

  float linv = 1.f / lrow;
  float r4[4];
  #pragma unroll
  for (int r = 0; r < 4; ++r) r4[r] = bperm_f(lg * 4 + r, linv);
  short* aob = ao + ((size_t)b * NPIX + qrow) * CH;
  #pragma unroll
  for (int j = 0; j < 16; ++j) {
    int cb2 = h * 16 + j;
    #pragma unroll
    for (int r = 0; r < 4; ++r) {
      aob[(size_t)(lg * 4 + r) * CH + cb2 * 16 + l15] = f2bf(oacc[j][r] * r4[r]);
    }
  }
}

// ---------------- kernel 5: proj GEMM + bias + residual (fp32 out)
__global__ __launch_bounds__(256) void proj_kernel(
    const short* __restrict__ wpm, const short* __restrict__ ao,
    const float* __restrict__ x, const float* __restrict__ pb,
    float* __restrict__ out) {
  int b = blockIdx.z;
  int tid = threadIdx.x;
  int lane = tid & 63, wid = tid >> 6;
  int l15 = lane & 15, lg = lane >> 4;
  int ob = blockIdx.y * 64 + (wid >> 1) * 32;
  int nbase = blockIdx.x * 64 + (wid & 1) * 32;
  const short* aptr = wpm + (size_t)(ob + l15) * CH + lg * 8;
  const short* bptr = ao + ((size_t)b * NPIX + nbase + l15) * CH + lg * 8;
  f32x4 acc[2][2];
  #pragma unroll
  for (int mi = 0; mi < 2; ++mi)
    #pragma unroll
    for (int ni = 0; ni < 2; ++ni) acc[mi][ni] = (f32x4){0.f, 0.f, 0.f, 0.f};
  #pragma unroll 4
  for (int kk = 0; kk < CH; kk += 32) {
    bf16x8 a0 = *reinterpret_cast<const bf16x8*>(aptr + kk);
    bf16x8 a1 = *reinterpret_cast<const bf16x8*>(aptr + 16 * CH + kk);
    bf16x8 b0 = *reinterpret_cast<const bf16x8*>(bptr + kk);
    bf16x8 b1 = *reinterpret_cast<const bf16x8*>(bptr + 16 * CH + kk);
    acc[0][0] = MFMA(a0, b0, acc[0][0], 0, 0, 0);
    acc[0][1] = MFMA(a0, b1, acc[0][1], 0, 0, 0);
    acc[1][0] = MFMA(a1, b0, acc[1][0], 0, 0, 0);
    acc[1][1] = MFMA(a1, b1, acc[1][1], 0, 0, 0);
  }
  #pragma unroll
  for (int mi = 0; mi < 2; ++mi) {
    int oo = ob + mi * 16 + lg * 4;
    #pragma unroll
    for (int ni = 0; ni < 2; ++ni) {
      int nn = nbase + ni * 16 + l15;
      #pragma unroll
      for (int r = 0; r < 4; ++r) {
        size_t idx = ((size_t)b * CH + oo + r) * NPIX + nn;
        out[idx] = acc[mi][ni][r] + pb[oo + r] + x[idx];
      }
    }
  }
}

extern "C" void kernel_launch(void* const* d_in, const int* in_sizes, int n_in,
                              void* d_out, int out_size, void* d_ws, size_t ws_size,
                              hipStream_t stream) {
  const float* x  = (const float*)d_in[0];
  const float* nw = (const float*)d_in[1];
  const float* nb = (const float*)d_in[2];
  const float* qw = (const float*)d_in[3];
  const float* qb = (const float*)d_in[4];
  const float* kw = (const float*)d_in[5];
  const float* kb = (const float*)d_in[6];
  const float* vw = (const float*)d_in[7];
  const float* vb = (const float*)d_in[8];
  const float* pw = (const float*)d_in[9];
  const float* pb = (const float*)d_in[10];
  char* ws = (char*)d_ws;
  short* wstack = (short*)(ws);                    // 1,572,864
  short* wp     = (short*)(ws + 1572864);          //   524,288
  short* hT     = (short*)(ws + 2101248);          // 16,777,216
  short* qT     = (short*)(ws + 18878464);         // 16,777,216
  short* kT     = (short*)(ws + 35655680);         // 16,777,216
  short* vC     = (short*)(ws + 52432896);         // 16,777,216 (end 69,210,112)
  short* ao     = hT;                              // hT dead after qkv
  float* out = (float*)d_out;

  hipFuncSetAttribute((const void*)flash_kernel,
                      hipFuncAttributeMaxDynamicSharedMemorySize, DYN_LDS);
  hipFuncSetAttribute((const void*)qkv_kernel,
                      hipFuncAttributeMaxDynamicSharedMemorySize, QKV_LDS);

  wconv_kernel<<<1024, 256, 0, stream>>>(qw, kw, vw, pw, wstack, wp);
  gn_kernel<<<256, 256, 0, stream>>>(x, nw, nb, hT);
  qkv_kernel<<<dim3(32, 12, NB), 256, QKV_LDS, stream>>>(wstack, hT, qb, kb, vb, qT, kT, vC);
  flash_kernel<<<dim3(64, NB), 512, DYN_LDS, stream>>>(qT, kT, vC, ao);
  proj_kernel<<<dim3(64, 8, NB), 256, 0, stream>>>(wp, ao, x, pb, out);
}

// Round 10
// 435.091 us; speedup vs baseline: 1.6884x; 1.0840x over previous
//
#include <hip/hip_runtime.h>

#define NB 4
#define CH 512
#define NPIX 4096
#define GSZ 16
#define KVB 32
#define NT (NPIX / KVB)          // 128 kv tiles
#define DYN_LDS 136192           // 64K K dbuf + 64K V dbuf + 4K P + 1K exch
#define GEMM_LDS 65536           // 2 x (128x64 A + 128x64 B) bf16

typedef __attribute__((ext_vector_type(8))) short bf16x8;
typedef __attribute__((ext_vector_type(4))) short bf16x4;
typedef __attribute__((ext_vector_type(4))) float f32x4;

#define MFMA __builtin_amdgcn_mfma_f32_16x16x32_bf16

static __device__ __forceinline__ short f2bf(float f) {
  unsigned u = __builtin_bit_cast(unsigned, f);
  u += 0x7fffu + ((u >> 16) & 1u);
  return (short)(u >> 16);
}

static __device__ __forceinline__ float bperm_f(int srclane, float v) {
  int r = __builtin_amdgcn_ds_bpermute(srclane << 2, __builtin_bit_cast(int, v));
  return __builtin_bit_cast(float, r);
}

typedef __attribute__((address_space(1))) unsigned glob_u32;
typedef __attribute__((address_space(3))) unsigned lds_u32;
static __device__ __forceinline__ void gl_lds16(const void* g, void* l) {
  __builtin_amdgcn_global_load_lds((const glob_u32*)g, (lds_u32*)l, 16, 0, 0);
}

// ---------------- kernel 1: weights fp32 -> bf16 (q,k,v stacked; proj separate)
__global__ __launch_bounds__(256) void wconv_kernel(
    const float* __restrict__ qw, const float* __restrict__ kw,
    const float* __restrict__ vw, const float* __restrict__ pw,
    short* __restrict__ wstack, short* __restrict__ wp) {
  int idx = (blockIdx.x * 256 + threadIdx.x) * 4;
  int mat = idx >> 18;
  int off = idx & 262143;
  const float* src = (mat == 0) ? qw : (mat == 1) ? kw : (mat == 2) ? vw : pw;
  short* dst = (mat < 3) ? (wstack + (size_t)mat * 262144) : wp;
  float4 v = *reinterpret_cast<const float4*>(src + off);
  bf16x4 o;
  o[0] = f2bf(v.x); o[1] = f2bf(v.y); o[2] = f2bf(v.z); o[3] = f2bf(v.w);
  *reinterpret_cast<bf16x4*>(dst + off) = o;
}

// ---------------- kernel 2: GroupNorm + bf16 + transpose -> hT [B][N][C]
// grid 256: two blocks per (b,g); stats redundant, normalize split by half.
__global__ __launch_bounds__(256) void gn_kernel(
    const float* __restrict__ x, const float* __restrict__ nw,
    const float* __restrict__ nb, short* __restrict__ hT) {
  int pairid = blockIdx.x >> 1, half = blockIdx.x & 1;
  int b = pairid >> 5, g = pairid & 31;
  int tid = threadIdx.x;
  const float* base = x + (size_t)(b * CH + g * GSZ) * NPIX;
  const float4* b4 = reinterpret_cast<const float4*>(base);
  float s = 0.f, s2 = 0.f;
  for (int i = tid; i < GSZ * NPIX / 4; i += 256) {
    float4 v = b4[i];
    s += v.x + v.y + v.z + v.w;
    s2 += v.x * v.x + v.y * v.y + v.z * v.z + v.w * v.w;
  }
  #pragma unroll
  for (int m = 1; m < 64; m <<= 1) { s += __shfl_xor(s, m); s2 += __shfl_xor(s2, m); }
  __shared__ float red[8];
  if ((tid & 63) == 0) { red[(tid >> 6) * 2] = s; red[(tid >> 6) * 2 + 1] = s2; }
  __syncthreads();
  s = red[0] + red[2] + red[4] + red[6];
  s2 = red[1] + red[3] + red[5] + red[7];
  float mean = s * (1.f / 65536.f);
  float var = s2 * (1.f / 65536.f) - mean * mean;
  float rstd = rsqrtf(var + 1e-5f);
  int c = tid >> 4, nq = tid & 15;
  float wch = nw[g * GSZ + c] * rstd;
  float bch = nb[g * GSZ + c] - mean * wch;
  __shared__ short lt[GSZ][264];
  short* outb = hT + (size_t)b * NPIX * CH + g * GSZ;
  const float* srcc = base + (size_t)c * NPIX + nq * 16;
  for (int chunk = half * 8; chunk < half * 8 + 8; ++chunk) {
    const float4* sp = reinterpret_cast<const float4*>(srcc + chunk * 256);
    float4 v0 = sp[0], v1 = sp[1], v2 = sp[2], v3 = sp[3];
    bf16x8 w0, w1;
    w0[0] = f2bf(v0.x * wch + bch); w0[1] = f2bf(v0.y * wch + bch);
    w0[2] = f2bf(v0.z * wch + bch); w0[3] = f2bf(v0.w * wch + bch);
    w0[4] = f2bf(v1.x * wch + bch); w0[5] = f2bf(v1.y * wch + bch);
    w0[6] = f2bf(v1.z * wch + bch); w0[7] = f2bf(v1.w * wch + bch);
    w1[0] = f2bf(v2.x * wch + bch); w1[1] = f2bf(v2.y * wch + bch);
    w1[2] = f2bf(v2.z * wch + bch); w1[3] = f2bf(v2.w * wch + bch);
    w1[4] = f2bf(v3.x * wch + bch); w1[5] = f2bf(v3.y * wch + bch);
    w1[6] = f2bf(v3.z * wch + bch); w1[7] = f2bf(v3.w * wch + bch);
    *reinterpret_cast<bf16x8*>(&lt[c][nq * 16]) = w0;
    *reinterpret_cast<bf16x8*>(&lt[c][nq * 16 + 8]) = w1;
    __syncthreads();
    bf16x8 o0, o1;
    #pragma unroll
    for (int cc = 0; cc < 8; ++cc) o0[cc] = lt[cc][tid];
    #pragma unroll
    for (int cc = 0; cc < 8; ++cc) o1[cc] = lt[cc + 8][tid];
    short* orow = outb + (size_t)(chunk * 256 + tid) * CH;
    *reinterpret_cast<bf16x8*>(orow) = o0;
    *reinterpret_cast<bf16x8*>(orow + 8) = o1;
    __syncthreads();
  }
}

// ---------------- kernel 3: QKV GEMM, m97-style 128x128xBK64 double-buffered
__global__ __launch_bounds__(256) void qkv_kernel(
    const short* __restrict__ wstack, const short* __restrict__ hT,
    const float* __restrict__ qb, const float* __restrict__ kb,
    const float* __restrict__ vb,
    short* __restrict__ qT, short* __restrict__ kT, short* __restrict__ vC) {
  extern __shared__ char qsm[];
  char* abuf = qsm;                 // [2][128][128B] weights tile
  char* bbuf = qsm + 32768;         // [2][128][128B] hT tile

  int b = blockIdx.z;
  int by = blockIdx.y;              // 0..11 (q 0-3, k 4-7, v 8-11)
  int nbase = blockIdx.x * 128;
  int tid = threadIdx.x;
  int lane = tid & 63, wid = tid >> 6;
  int l15 = lane & 15, lg = lane >> 4;
  int wr = wid >> 1, wc = wid & 1;

  const short* arows = wstack + (size_t)by * 128 * CH;
  const short* brows = hT + ((size_t)b * NPIX + nbase) * CH;

  auto stage = [&](int buf, int kidx) {
    char* ad = abuf + buf * 16384;
    char* bd = bbuf + buf * 16384;
    #pragma unroll
    for (int i = 0; i < 4; ++i) {
      int off = i * 4096 + tid * 16;
      int row = off >> 7;
      int c16 = (off >> 4) & 7;
      int gchunk = (c16 ^ (row & 7)) * 8;
      gl_lds16(arows + (size_t)row * CH + kidx * 64 + gchunk, ad + off);
      gl_lds16(brows + (size_t)row * CH + kidx * 64 + gchunk, bd + off);
    }
  };

  f32x4 acc[4][4];
  #pragma unroll
  for (int mi = 0; mi < 4; ++mi)
    #pragma unroll
    for (int ni = 0; ni < 4; ++ni) acc[mi][ni] = (f32x4){0.f, 0.f, 0.f, 0.f};

  stage(0, 0);
  __syncthreads();

  int cur = 0;
  for (int kt = 0; kt < 8; ++kt) {
    if (kt + 1 < 8) stage(cur ^ 1, kt + 1);
    const char* ab = abuf + cur * 16384;
    const char* bb = bbuf + cur * 16384;
    #pragma unroll
    for (int ks = 0; ks < 2; ++ks) {
      bf16x8 af[4], bf[4];
      #pragma unroll
      for (int mi = 0; mi < 4; ++mi) {
        int row = wr * 64 + mi * 16 + l15;
        af[mi] = *reinterpret_cast<const bf16x8*>(
            ab + row * 128 + (((ks * 4 + lg) ^ (row & 7)) << 4));
      }
      #pragma unroll
      for (int ni = 0; ni < 4; ++ni) {
        int row = wc * 64 + ni * 16 + l15;
        bf[ni] = *reinterpret_cast<const bf16x8*>(
            bb + row * 128 + (((ks * 4 + lg) ^ (row & 7)) << 4));
      }
      #pragma unroll
      for (int mi = 0; mi < 4; ++mi)
        #pragma unroll
        for (int ni = 0; ni < 4; ++ni)
          acc[mi][ni] = MFMA(af[mi], bf[ni], acc[mi][ni], 0, 0, 0);
    }
    __syncthreads();
    cur ^= 1;
  }

  int oglob = by * 128;
  #pragma unroll
  for (int mi = 0; mi < 4; ++mi) {
    int oo = oglob + (wid >> 1) * 64 + mi * 16 + lg * 4;
    #pragma unroll
    for (int ni = 0; ni < 4; ++ni) {
      int nn = nbase + (wid & 1) * 64 + ni * 16 + l15;
      f32x4 a = acc[mi][ni];
      if (oglob < 1024) {
        const float* bias = (oglob < 512) ? qb : kb;
        short* dstm = (oglob < 512) ? qT : kT;
        float sc = (oglob < 512) ? 0.044194173824159216f : 1.0f;
        int ol = oo & 511;
        bf16x4 pk;
        #pragma unroll
        for (int r = 0; r < 4; ++r) pk[r] = f2bf((a[r] + bias[ol + r]) * sc);
        *reinterpret_cast<bf16x4*>(dstm + ((size_t)b * NPIX + nn) * CH + ol) = pk;
      } else {
        int ov = oo - 1024;
        short* dstv = vC + ((size_t)b * CH + ov) * NPIX + nn;
        #pragma unroll
        for (int r = 0; r < 4; ++r) dstv[(size_t)r * NPIX] = f2bf(a[r] + vb[ov + r]);
      }
    }
  }
}

// ---------------- kernel 4: flash attention (R6-best), 8 waves, kv-split
// pairs, swapped QK^T (per-lane softmax), PV delayed one iter, pipelined.
// Only change vs R9: QK accumulator split into 2 interleaved chains.
__global__ __launch_bounds__(512, 2) void flash_kernel(
    const short* __restrict__ qT, const short* __restrict__ kT,
    const short* __restrict__ vC, short* __restrict__ ao) {
  extern __shared__ char smem[];
  char* kbuf = smem;                         // [2][32][1024B] K (XOR-swz)
  char* vbuf = smem + 65536;                 // [2][512][64B]  V (XOR-swz)
  char* pbuf = smem + 131072;                // [4 pairs][16q][64B] P~ (XOR-swz)
  float* exch = (float*)(smem + 135168);     // [8 waves][16q][2] (m, psum)

  int lin = blockIdx.y * 64 + blockIdx.x;    // 0..255
  int sw = (lin & 7) * 32 + (lin >> 3);      // XCD swizzle (256 % 8 == 0)
  int qb = sw & 63, b = sw >> 6;

  int tid = threadIdx.x;
  int lane = tid & 63, w = tid >> 6;         // 8 waves
  int p = w >> 1, h = w & 1;                 // pair, kv/d-half
  int l15 = lane & 15, lg = lane >> 4;
  int qrow = qb * 64 + p * 16;

  const short* qptr = qT + ((size_t)b * NPIX + qrow + l15) * CH + lg * 8;
  bf16x8 qf[16];
  #pragma unroll
  for (int ks = 0; ks < 16; ++ks) qf[ks] = *reinterpret_cast<const bf16x8*>(qptr + ks * 32);

  f32x4 oacc[16];
  #pragma unroll
  for (int i = 0; i < 16; ++i) oacc[i] = (f32x4){0.f, 0.f, 0.f, 0.f};
  float mrow = -INFINITY, lrow = 0.f;        // per-lane: q = l15
  bf16x8 pa_prev;
  bf16x8 vf_prev[16];
  #pragma unroll
  for (int i = 0; i < 8; ++i) pa_prev[i] = 0;
  #pragma unroll
  for (int j = 0; j < 16; ++j)
    #pragma unroll
    for (int i = 0; i < 8; ++i) vf_prev[j][i] = 0;

  const short* kTb = kT + (size_t)b * NPIX * CH;
  const short* vCb = vC + (size_t)b * CH * NPIX;
  const int swz = (l15 & 7) << 4;
  const int vswz = ((l15 >> 1) & 3) << 4;
  const int pswz = (l15 & 3) << 4;
  char* ppair = pbuf + p * 1024;
  float* exw = exch + (w * 16 + l15) * 2;          // own slot
  float* exr = exch + ((w ^ 1) * 16 + l15) * 2;    // partner slot

  auto stage = [&](int buf, int t) {
    int m0 = t * KVB;
    char* kd = kbuf + buf * 32768;
    char* vd = vbuf + buf * 32768;
    #pragma unroll
    for (int i = 0; i < 4; ++i) {            // K rows (src pre-swizzled)
      int r = w * 4 + i;
      const short* src = kTb + (size_t)(m0 + r) * CH + ((lane ^ (r & 7)) * 8);
      gl_lds16(src, kd + r * 1024);
    }
    #pragma unroll
    for (int i = 0; i < 4; ++i) {            // V chunks (src pre-swizzled)
      int j = w * 4 + i;
      int ch = j * 16 + (lane >> 2);
      const short* src = vCb + (size_t)ch * NPIX + m0 +
                         (((lane & 3) ^ ((lane >> 3) & 3)) * 8);
      gl_lds16(src, vd + j * 1024);
    }
  };

  stage(0, 0);
  asm volatile("s_waitcnt vmcnt(0)" ::: "memory");
  __syncthreads();

  int cur = 0;
  for (int t = 0; t < NT; ++t) {
    const char* kb_ = kbuf + cur * 32768;
    const char* vb_ = vbuf + cur * 32768;
    // ---- 0. issue next-tile staging NOW; drained only at bar2 (full cover)
    if (t + 1 < NT) stage(cur ^ 1, t + 1);
    // ---- 1. swapped QK: S^T[16kv(h), 16q] = K_h * Q^T, 2 interleaved chains
    f32x4 sa = (f32x4){0.f, 0.f, 0.f, 0.f};
    f32x4 sb = (f32x4){0.f, 0.f, 0.f, 0.f};
    __builtin_amdgcn_s_setprio(1);
    #pragma unroll
    for (int cs = 0; cs < 16; cs += 2) {
      bf16x8 kf0 = *reinterpret_cast<const bf16x8*>(
          kb_ + (h * 16 + l15) * 1024 + ((cs * 64 + lg * 16) ^ swz));
      bf16x8 kf1 = *reinterpret_cast<const bf16x8*>(
          kb_ + (h * 16 + l15) * 1024 + (((cs + 1) * 64 + lg * 16) ^ swz));
      sa = MFMA(kf0, qf[cs], sa, 0, 0, 0);
      sb = MFMA(kf1, qf[cs + 1], sb, 0, 0, 0);
    }
    __builtin_amdgcn_s_setprio(0);
    f32x4 st = sa + sb;
    // ---- 2. own-half reduce
    float tmax = fmaxf(fmaxf(st[0], st[1]), fmaxf(st[2], st[3]));
    tmax = fmaxf(tmax, __shfl_xor(tmax, 16));
    tmax = fmaxf(tmax, __shfl_xor(tmax, 32));
    float pr[4];
    float psh;
    pr[0] = __expf(st[0] - tmax); pr[1] = __expf(st[1] - tmax);
    pr[2] = __expf(st[2] - tmax); pr[3] = __expf(st[3] - tmax);
    psh = (pr[0] + pr[1]) + (pr[2] + pr[3]);
    psh += __shfl_xor(psh, 16);
    psh += __shfl_xor(psh, 32);
    if (lane < 16) { exw[0] = tmax; exw[1] = psh; }
    // ---- bar1: LDS-only drain; staging stays in flight (no vmcnt)
    asm volatile("s_waitcnt lgkmcnt(0)" ::: "memory");
    __builtin_amdgcn_s_barrier();
    __builtin_amdgcn_sched_barrier(0);
    // ---- 3. combine with partner half
    float mo = exr[0], po = exr[1];
    float mnew = fmaxf(mrow, fmaxf(tmax, mo));
    float alpha = __expf(mrow - mnew);
    float scl = __expf(tmax - mnew);
    lrow = lrow * alpha + psh * scl + po * __expf(mo - mnew);
    mrow = mnew;
    // ---- 4. P~ = P_h * scl -> LDS
    {
      bf16x4 pk;
      pk[0] = f2bf(pr[0] * scl); pk[1] = f2bf(pr[1] * scl);
      pk[2] = f2bf(pr[2] * scl); pk[3] = f2bf(pr[3] * scl);
      *reinterpret_cast<bf16x4*>(ppair + l15 * 64 + ((h * 32 + lg * 8) ^ pswz)) = pk;
    }
    // ---- 5. PV(t-1) in registers, then rescale by alpha
    __builtin_amdgcn_s_setprio(1);
    #pragma unroll
    for (int j = 0; j < 16; ++j)
      oacc[j] = MFMA(pa_prev, vf_prev[j], oacc[j], 0, 0, 0);
    __builtin_amdgcn_s_setprio(0);
    if (!__all(alpha == 1.0f)) {
      float a4[4];
      #pragma unroll
      for (int r = 0; r < 4; ++r) a4[r] = bperm_f(lg * 4 + r, alpha);
      #pragma unroll
      for (int j = 0; j < 16; ++j) {
        oacc[j][0] *= a4[0]; oacc[j][1] *= a4[1];
        oacc[j][2] *= a4[2]; oacc[j][3] *= a4[3];
      }
    }
    // ---- 5.5 register prefetch of V(t) fragments
    #pragma unroll
    for (int j = 0; j < 16; ++j)
      vf_prev[j] = *reinterpret_cast<const bf16x8*>(
          vb_ + ((h * 16 + j) * 16 + l15) * 64 + ((lg * 16) ^ vswz));
    // ---- bar2: staged tile t+1 + P~ visible
    asm volatile("s_waitcnt vmcnt(0) lgkmcnt(0)" ::: "memory");
    __builtin_amdgcn_s_barrier();
    __builtin_amdgcn_sched_barrier(0);
    // ---- 7. P~(t) fragment for next-iter PV
    pa_prev = *reinterpret_cast<const bf16x8*>(ppair + l15 * 64 + ((lg * 16) ^ pswz));
    cur ^= 1;
  }
  // ---- final PV for last tile
  #pragma unroll
  for (int j = 0; j < 16; ++j)
    oacc[j] = MFMA(pa_prev, vf_prev[j], oacc[j], 0, 0, 0);

  float linv = 1.f / lrow;
  float r4[4];
  #pragma unroll
  for (int r = 0; r < 4; ++r) r4[r] = bperm_f(lg * 4 + r, linv);
  short* aob = ao + ((size_t)b * NPIX + qrow) * CH;
  #pragma unroll
  for (int j = 0; j < 16; ++j) {
    int cb2 = h * 16 + j;
    #pragma unroll
    for (int r = 0; r < 4; ++r) {
      aob[(size_t)(lg * 4 + r) * CH + cb2 * 16 + l15] = f2bf(oacc[j][r] * r4[r]);
    }
  }
}

// ---------------- kernel 5: proj GEMM, m97-style 128x128xBK64 double-buffered
// LDS staging + fused bias + fp32 residual. A = wp [512][512], B = ao [B][N][C].
__global__ __launch_bounds__(256) void proj_kernel(
    const short* __restrict__ wpm, const short* __restrict__ ao,
    const float* __restrict__ x, const float* __restrict__ pb,
    float* __restrict__ out) {
  extern __shared__ char qsm[];
  char* abuf = qsm;                 // [2][128][128B] weights tile
  char* bbuf = qsm + 32768;         // [2][128][128B] ao tile

  int b = blockIdx.z;
  int by = blockIdx.y;              // 0..3 (o block of 128)
  int nbase = blockIdx.x * 128;
  int tid = threadIdx.x;
  int lane = tid & 63, wid = tid >> 6;
  int l15 = lane & 15, lg = lane >> 4;
  int wr = wid >> 1, wc = wid & 1;

  const short* arows = wpm + (size_t)by * 128 * CH;
  const short* brows = ao + ((size_t)b * NPIX + nbase) * CH;

  auto stage = [&](int buf, int kidx) {
    char* ad = abuf + buf * 16384;
    char* bd = bbuf + buf * 16384;
    #pragma unroll
    for (int i = 0; i < 4; ++i) {
      int off = i * 4096 + tid * 16;
      int row = off >> 7;
      int c16 = (off >> 4) & 7;
      int gchunk = (c16 ^ (row & 7)) * 8;
      gl_lds16(arows + (size_t)row * CH + kidx * 64 + gchunk, ad + off);
      gl_lds16(brows + (size_t)row * CH + kidx * 64 + gchunk, bd + off);
    }
  };

  f32x4 acc[4][4];
  #pragma unroll
  for (int mi = 0; mi < 4; ++mi)
    #pragma unroll
    for (int ni = 0; ni < 4; ++ni) acc[mi][ni] = (f32x4){0.f, 0.f, 0.f, 0.f};

  stage(0, 0);
  __syncthreads();

  int cur = 0;
  for (int kt = 0; kt < 8; ++kt) {
    if (kt + 1 < 8) stage(cur ^ 1, kt + 1);
    const char* ab = abuf + cur * 16384;
    const char* bb = bbuf + cur * 16384;
    #pragma unroll
    for (int ks = 0; ks < 2; ++ks) {
      bf16x8 af[4], bf[4];
      #pragma unroll
      for (int mi = 0; mi < 4; ++mi) {
        int row = wr * 64 + mi * 16 + l15;
        af[mi] = *reinterpret_cast<const bf16x8*>(
            ab + row * 128 + (((ks * 4 + lg) ^ (row & 7)) << 4));
      }
      #pragma unroll
      for (int ni = 0; ni < 4; ++ni) {
        int row = wc * 64 + ni * 16 + l15;
        bf[ni] = *reinterpret_cast<const bf16x8*>(
            bb + row * 128 + (((ks * 4 + lg) ^ (row & 7)) << 4));
      }
      #pragma unroll
      for (int mi = 0; mi < 4; ++mi)
        #pragma unroll
        for (int ni = 0; ni < 4; ++ni)
          acc[mi][ni] = MFMA(af[mi], bf[ni], acc[mi][ni], 0, 0, 0);
    }
    __syncthreads();
    cur ^= 1;
  }

  #pragma unroll
  for (int mi = 0; mi < 4; ++mi) {
    int oo = by * 128 + wr * 64 + mi * 16 + lg * 4;
    #pragma unroll
    for (int ni = 0; ni < 4; ++ni) {
      int nn = nbase + wc * 64 + ni * 16 + l15;
      f32x4 a = acc[mi][ni];
      #pragma unroll
      for (int r = 0; r < 4; ++r) {
        size_t idx = ((size_t)b * CH + oo + r) * NPIX + nn;
        out[idx] = a[r] + pb[oo + r] + x[idx];
      }
    }
  }
}

extern "C" void kernel_launch(void* const* d_in, const int* in_sizes, int n_in,
                              void* d_out, int out_size, void* d_ws, size_t ws_size,
                              hipStream_t stream) {
  const float* x  = (const float*)d_in[0];
  const float* nw = (const float*)d_in[1];
  const float* nb = (const float*)d_in[2];
  const float* qw = (const float*)d_in[3];
  const float* qb = (const float*)d_in[4];
  const float* kw = (const float*)d_in[5];
  const float* kb = (const float*)d_in[6];
  const float* vw = (const float*)d_in[7];
  const float* vb = (const float*)d_in[8];
  const float* pw = (const float*)d_in[9];
  const float* pb = (const float*)d_in[10];
  char* ws = (char*)d_ws;
  short* wstack = (short*)(ws);                    // 1,572,864
  short* wp     = (short*)(ws + 1572864);          //   524,288
  short* hT     = (short*)(ws + 2101248);          // 16,777,216
  short* qT     = (short*)(ws + 18878464);         // 16,777,216
  short* kT     = (short*)(ws + 35655680);         // 16,777,216
  short* vC     = (short*)(ws + 52432896);         // 16,777,216 (end 69,210,112)
  short* ao     = hT;                              // hT dead after qkv
  float* out = (float*)d_out;

  hipFuncSetAttribute((const void*)flash_kernel,
                      hipFuncAttributeMaxDynamicSharedMemorySize, DYN_LDS);
  hipFuncSetAttribute((const void*)qkv_kernel,
                      hipFuncAttributeMaxDynamicSharedMemorySize, GEMM_LDS);
  hipFuncSetAttribute((const void*)proj_kernel,
                      hipFuncAttributeMaxDynamicSharedMemorySize, GEMM_LDS);

  wconv_kernel<<<1024, 256, 0, stream>>>(qw, kw, vw, pw, wstack, wp);
  gn_kernel<<<256, 256, 0, stream>>>(x, nw, nb, hT);
  qkv_kernel<<<dim3(32, 12, NB), 256, GEMM_LDS, stream>>>(wstack, hT, qb, kb, vb, qT, kT, vC);
  flash_kernel<<<dim3(64, NB), 512, DYN_LDS, stream>>>(qT, kT, vC, ao);
  proj_kernel<<<dim3(32, 4, NB), 256, GEMM_LDS, stream>>>(wp, ao, x, pb, out);
}